// Round 15
// baseline (1640.637 us; speedup 1.0000x reference)
//
#include <hip/hip_runtime.h>
#include <cmath>

#define BATCH  2
#define SEQ    2048
#define DMODEL 1024
#define NHEAD  16
#define HDIM   64
#define KTOP   8
#define KKEEP  10   // global top-8 + slack for bitwise ties at the threshold
#define LKEEP  12   // lane-local FMA-prefilter candidates (margin vs delta)

// KC=512 CONFIRMED bit-exact vs harness numpy reference (rounds 6/8-14 pass).
#define KC_PANEL 512

// ---------------------------------------------------------------------------
// Projection GEMM replicating OpenBLAS sgemm fp32 rounding (KC=512 panels).
// MODE 0: out in head layout [b][h][s][d]; MODE 1: flat [row][col].
// ---------------------------------------------------------------------------
template<int MODE>
__global__ __launch_bounds__(256)
void proj_gemm(const float* __restrict__ A, const float* __restrict__ W,
               const float* __restrict__ bias, float* __restrict__ outp)
{
    __shared__ float As[32][68];   // [k][m]
    __shared__ float Bs[32][68];   // [k][n]
    const int tid  = threadIdx.x;
    const int tx   = tid & 15, ty = tid >> 4;
    const int row0 = blockIdx.x * 64;
    const int col0 = blockIdx.y * 64;
    const int lm   = tid >> 2;          // 0..63
    const int lk   = (tid & 3) * 8;     // 0,8,16,24

    float acc[4][4] = {};   // open panel chain
    float sum[4][4] = {};   // closed panels

    for (int kb = 0; kb < DMODEL; kb += 32) {
        if (kb && (kb % KC_PANEL == 0)) {
            #pragma unroll
            for (int i = 0; i < 4; ++i)
                #pragma unroll
                for (int j = 0; j < 4; ++j) { sum[i][j] += acc[i][j]; acc[i][j] = 0.f; }
        }
        __syncthreads();
        const float* srcA = A + (size_t)(row0 + lm) * DMODEL + kb + lk;
        float4 a0 = *(const float4*)srcA;
        float4 a1 = *(const float4*)(srcA + 4);
        const float* srcB = W + (size_t)(col0 + lm) * DMODEL + kb + lk;
        float4 b0 = *(const float4*)srcB;
        float4 b1 = *(const float4*)(srcB + 4);
        As[lk+0][lm]=a0.x; As[lk+1][lm]=a0.y; As[lk+2][lm]=a0.z; As[lk+3][lm]=a0.w;
        As[lk+4][lm]=a1.x; As[lk+5][lm]=a1.y; As[lk+6][lm]=a1.z; As[lk+7][lm]=a1.w;
        Bs[lk+0][lm]=b0.x; Bs[lk+1][lm]=b0.y; Bs[lk+2][lm]=b0.z; Bs[lk+3][lm]=b0.w;
        Bs[lk+4][lm]=b1.x; Bs[lk+5][lm]=b1.y; Bs[lk+6][lm]=b1.z; Bs[lk+7][lm]=b1.w;
        __syncthreads();
        #pragma unroll
        for (int kk = 0; kk < 32; ++kk) {   // ascending k, fused-FMA chain
            float4 af = *(const float4*)&As[kk][ty*4];
            float4 bf = *(const float4*)&Bs[kk][tx*4];
            float a_[4] = {af.x, af.y, af.z, af.w};
            float b_[4] = {bf.x, bf.y, bf.z, bf.w};
            #pragma unroll
            for (int i = 0; i < 4; ++i)
                #pragma unroll
                for (int j = 0; j < 4; ++j)
                    acc[i][j] = fmaf(a_[i], b_[j], acc[i][j]);
        }
    }

    #pragma unroll
    for (int i = 0; i < 4; ++i) {
        const int row = row0 + ty*4 + i;
        const int bb  = row >> 11;
        const int ss  = row & (SEQ - 1);
        #pragma unroll
        for (int j = 0; j < 4; ++j) {
            const int col = col0 + tx*4 + j;
            float r = sum[i][j] + acc[i][j];   // close final panel
            r = r + bias[col];                 // bias == 0.0f: exact
            if constexpr (MODE == 1) {
                outp[(size_t)row * DMODEL + col] = r;
            } else {
                const int h = col >> 6, d = col & 63;
                outp[(((size_t)(bb*NHEAD + h))*SEQ + ss)*HDIM + d] = r;
            }
        }
    }
}

// ---------------------------------------------------------------------------
// Attention, lane = query row, waves split keys 4-way, 2-deep key prefetch
// (R14 structure, VGPR=148/SGPR-scalarized K loads, no spill). NEW vs R14:
// FMA PREFILTER + EXACT RESCORE.
//   Scan: fmaf dot (64 FMA vs 128 mul/add -- the numpy rounding is NOT needed
//   to find candidates), keep lane-local top-LKEEP=12 (value,index).
//   Then: re-score those 12 indices with the exact npyv cascade (bit-exact
//   numpy einsum rounding), canonical sort (v desc, ix asc), and the verified
//   exact 4-way merge + softmax + PV on EXACT values.
//   Margin: |fma - npyv| <= ~4e-6 abs; losing an exact-local-top-10 key needs
//   >=3 adjacent order-stat gaps (mean ~9e-3) below that -> P ~ 7e-5 over the
//   whole dataset. Final selected values bit-identical by construction.
// ---------------------------------------------------------------------------
__global__ __launch_bounds__(256, 1)
void attn_topk(const float* __restrict__ Qh, const float* __restrict__ Kh,
               const float* __restrict__ Vh, float* __restrict__ AO)
{
    __shared__ float Ls[4][64][LKEEP + 1];   // +1 pad: 13*4B lane stride
    __shared__ int   Li[4][64][LKEEP + 1];
    const int tid  = threadIdx.x;
    const int lane = tid & 63;
    const int w    = tid >> 6;          // 0..3 (key quarter / dim quarter)
    const int bh   = blockIdx.x;        // 0..31  (XCD = bh % 8)
    const int rg   = blockIdx.y;        // 0..31
    const int srow = rg * 64 + lane;    // this lane's query row
    const size_t hbase = (size_t)bh * SEQ * HDIM;
    const float* Q = Qh + hbase;
    const float* K = Kh + hbase;
    const float* V = Vh + hbase;

    // ---- this lane's q row -> VGPRs ----
    float q[64];
    {
        const float* qsrc = Q + (size_t)srow * HDIM;
        #pragma unroll
        for (int d4 = 0; d4 < 16; ++d4) {
            float4 t4 = *(const float4*)(qsrc + d4*4);
            q[d4*4+0]=t4.x; q[d4*4+1]=t4.y; q[d4*4+2]=t4.z; q[d4*4+3]=t4.w;
        }
    }

    // ---- FMA-prefilter lane-local top-LKEEP over this wave's 512 keys ----
    float fv[LKEEP]; int fi[LKEEP];
    #pragma unroll
    for (int s = 0; s < LKEEP; ++s) { fv[s] = -INFINITY; fi[s] = 0; }

    const int k0 = w * (SEQ/4);

#define LOADKEY(buf, kidx)                                                  \
    do {                                                                    \
        const float* kb_ = K + (size_t)(kidx) * HDIM;                       \
        _Pragma("unroll")                                                   \
        for (int f_ = 0; f_ < 16; ++f_)                                     \
            buf[f_] = *(const float4*)(kb_ + 4*f_);                         \
    } while (0)

#define DOTINS_FMA(buf, kidx)                                               \
    do {                                                                    \
        float A0=0.f, A1=0.f, A2=0.f, A3=0.f;                               \
        _Pragma("unroll")                                                   \
        for (int t_ = 0; t_ < 4; ++t_) {                                    \
            _Pragma("unroll")                                               \
            for (int f_ = 0; f_ < 4; ++f_) {                                \
                const float4 k4_ = buf[t_*4+f_];                            \
                const int u_ = t_*16 + f_*4;                                \
                A0 = fmaf(q[u_+0], k4_.x, A0);                              \
                A1 = fmaf(q[u_+1], k4_.y, A1);                              \
                A2 = fmaf(q[u_+2], k4_.z, A2);                              \
                A3 = fmaf(q[u_+3], k4_.w, A3);                              \
            }                                                               \
        }                                                                   \
        const float cand_ = ((A0 + A1) + (A2 + A3)) * 0.125f;               \
        if (cand_ > fv[LKEEP-1]) {                                          \
            float v_ = cand_; int ix_ = (kidx);                             \
            _Pragma("unroll")                                               \
            for (int s_ = 0; s_ < LKEEP; ++s_) {                            \
                const bool gt_ = v_ > fv[s_];                               \
                const float o1_ = fv[s_]; const int o2_ = fi[s_];           \
                fv[s_] = gt_ ? v_  : o1_;  fi[s_] = gt_ ? ix_ : o2_;        \
                v_     = gt_ ? o1_ : v_;   ix_    = gt_ ? o2_ : ix_;        \
            }                                                               \
        }                                                                   \
    } while (0)

    {
        float4 bufA[16], bufB[16];
        LOADKEY(bufA, k0);                       // prologue: key 0
        for (int c = 0; c < SEQ/4; c += 2) {
            const int c1 = k0 + ((c+1 < SEQ/4) ? c+1 : SEQ/4-1);
            const int c2 = k0 + ((c+2 < SEQ/4) ? c+2 : SEQ/4-1);
            LOADKEY(bufB, c1);                   // issue c+1 loads ...
            DOTINS_FMA(bufA, k0 + c);            // ... under c's compute
            LOADKEY(bufA, c2);                   // issue c+2 loads ...
            DOTINS_FMA(bufB, c1);                // ... under c+1's compute
        }
    }
#undef LOADKEY
#undef DOTINS_FMA

    // ---- EXACT rescore of the 12 candidates (numpy npyv cascade, bit-exact;
    //      K rows gathered from L2; s is compile-time static -> registers) ----
    float ev[LKEEP];
    #pragma unroll
    for (int s = 0; s < LKEEP; ++s) {
        const float* kr = K + (size_t)fi[s] * HDIM;
        float4 kb[16];
        #pragma unroll
        for (int f = 0; f < 16; ++f) kb[f] = *(const float4*)(kr + 4*f);
        float raw;
        {
            #pragma clang fp contract(off)
            float A0=0.f,A1=0.f,A2=0.f,A3=0.f;
            #pragma unroll
            for (int t = 0; t < 4; ++t) {
                float kv[16];
                #pragma unroll
                for (int f = 0; f < 4; ++f) {
                    kv[f*4+0]=kb[t*4+f].x; kv[f*4+1]=kb[t*4+f].y;
                    kv[f*4+2]=kb[t*4+f].z; kv[f*4+3]=kb[t*4+f].w;
                }
                const int u = t*16;
                A0 = q[u+0]*kv[0] + (q[u+4]*kv[4] + (q[u+8]*kv[8]   + (q[u+12]*kv[12] + A0)));
                A1 = q[u+1]*kv[1] + (q[u+5]*kv[5] + (q[u+9]*kv[9]   + (q[u+13]*kv[13] + A1)));
                A2 = q[u+2]*kv[2] + (q[u+6]*kv[6] + (q[u+10]*kv[10] + (q[u+14]*kv[14] + A2)));
                A3 = q[u+3]*kv[3] + (q[u+7]*kv[7] + (q[u+11]*kv[11] + (q[u+15]*kv[15] + A3)));
            }
            raw = (A0 + A1) + (A2 + A3);
        }
        ev[s] = raw * 0.125f;    // /sqrt(64) exact
    }

    // ---- canonical local sort: (value desc, index asc) ----
    float tv[LKEEP]; int ti[LKEEP];
    #pragma unroll
    for (int s = 0; s < LKEEP; ++s) { tv[s] = -INFINITY; ti[s] = 0x7fffffff; }
    #pragma unroll
    for (int s = 0; s < LKEEP; ++s) {
        float v = ev[s]; int ix = fi[s];
        #pragma unroll
        for (int t = 0; t < LKEEP; ++t) {
            const bool gt = (v > tv[t]) || (v == tv[t] && ix < ti[t]);
            const float otv = tv[t]; const int oti = ti[t];
            tv[t] = gt ? v  : otv;  ti[t] = gt ? ix  : oti;
            v     = gt ? otv : v;   ix    = gt ? oti : ix;
        }
    }

    // ---- publish partial lists, one barrier ----
    #pragma unroll
    for (int s = 0; s < LKEEP; ++s) {
        Ls[w][lane][s] = tv[s];
        Li[w][lane][s] = ti[s];
    }
    __syncthreads();

    // ---- exact 4-way merge on EXACT values (pointer-walk, 10 steps) ----
    float gv[KKEEP]; int gi[KKEEP];
    {
        int   hp0 = 0, hp1 = 0, hp2 = 0, hp3 = 0;
        float hv0 = Ls[0][lane][0], hv1 = Ls[1][lane][0],
              hv2 = Ls[2][lane][0], hv3 = Ls[3][lane][0];
        int   hi0 = Li[0][lane][0], hi1 = Li[1][lane][0],
              hi2 = Li[2][lane][0], hi3 = Li[3][lane][0];
        #pragma unroll
        for (int s = 0; s < KKEEP; ++s) {
            float bv = hv0; int bi = hi0; int bj = 0;
            if (hv1 > bv || (hv1 == bv && hi1 < bi)) { bv = hv1; bi = hi1; bj = 1; }
            if (hv2 > bv || (hv2 == bv && hi2 < bi)) { bv = hv2; bi = hi2; bj = 2; }
            if (hv3 > bv || (hv3 == bv && hi3 < bi)) { bv = hv3; bi = hi3; bj = 3; }
            gv[s] = bv; gi[s] = bi;
            {
                const bool a = (bj == 0); const int np = hp0 + (a ? 1 : 0);
                const int  rp = np < LKEEP ? np : LKEEP-1;
                const float nv = Ls[0][lane][rp]; const int ni = Li[0][lane][rp];
                if (a) { hp0 = np; hv0 = (np < LKEEP) ? nv : -INFINITY; hi0 = ni; }
            }
            {
                const bool a = (bj == 1); const int np = hp1 + (a ? 1 : 0);
                const int  rp = np < LKEEP ? np : LKEEP-1;
                const float nv = Ls[1][lane][rp]; const int ni = Li[1][lane][rp];
                if (a) { hp1 = np; hv1 = (np < LKEEP) ? nv : -INFINITY; hi1 = ni; }
            }
            {
                const bool a = (bj == 2); const int np = hp2 + (a ? 1 : 0);
                const int  rp = np < LKEEP ? np : LKEEP-1;
                const float nv = Ls[2][lane][rp]; const int ni = Li[2][lane][rp];
                if (a) { hp2 = np; hv2 = (np < LKEEP) ? nv : -INFINITY; hi2 = ni; }
            }
            {
                const bool a = (bj == 3); const int np = hp3 + (a ? 1 : 0);
                const int  rp = np < LKEEP ? np : LKEEP-1;
                const float nv = Ls[3][lane][rp]; const int ni = Li[3][lane][rp];
                if (a) { hp3 = np; hv3 = (np < LKEEP) ? nv : -INFINITY; hi3 = ni; }
            }
        }
    }

    // ---- per-lane softmax over kept set (identical order to R6-R14) ----
    const float thr = gv[KTOP-1];
    const float m   = gv[0];
    float wv[KKEEP]; float wsum = 0.f;
    #pragma unroll
    for (int s = 0; s < KKEEP; ++s) {
        wv[s] = (gv[s] >= thr) ? expf(gv[s] - m) : 0.f;   // slots 8,9 iff tied
        wsum += wv[s];
    }

    // ---- sparse PV, this wave does dims [w*16, w*16+16) ----
    float o[16];
    #pragma unroll
    for (int d = 0; d < 16; ++d) o[d] = 0.f;
    #pragma unroll
    for (int s = 0; s < KKEEP; ++s) {
        const float wgt = wv[s] / wsum;                  // 0 for non-kept: exact
        const float* vrow = V + (size_t)gi[s] * HDIM + w * 16;
        #pragma unroll
        for (int d4 = 0; d4 < 4; ++d4) {
            float4 vv = *(const float4*)(vrow + d4*4);
            o[d4*4+0] = fmaf(wgt, vv.x, o[d4*4+0]);
            o[d4*4+1] = fmaf(wgt, vv.y, o[d4*4+1]);
            o[d4*4+2] = fmaf(wgt, vv.z, o[d4*4+2]);
            o[d4*4+3] = fmaf(wgt, vv.w, o[d4*4+3]);
        }
    }

    // AO flat layout [b][s][h*64+d]
    float* dst = AO + ((size_t)(bh >> 4) * SEQ + srow) * DMODEL
               + (bh & 15) * HDIM + w * 16;
    #pragma unroll
    for (int d4 = 0; d4 < 4; ++d4) {
        float4 ov; ov.x = o[d4*4+0]; ov.y = o[d4*4+1];
                   ov.z = o[d4*4+2]; ov.w = o[d4*4+3];
        *(float4*)(dst + d4*4) = ov;
    }
}

// ---------------------------------------------------------------------------
extern "C" void kernel_launch(void* const* d_in, const int* in_sizes, int n_in,
                              void* d_out, int out_size, void* d_ws, size_t ws_size,
                              hipStream_t stream)
{
    const float* q  = (const float*)d_in[0];
    const float* k  = (const float*)d_in[1];
    const float* v  = (const float*)d_in[2];
    const float* Wq = (const float*)d_in[3];
    const float* bq = (const float*)d_in[4];
    const float* Wk = (const float*)d_in[5];
    const float* bk = (const float*)d_in[6];
    const float* Wv = (const float*)d_in[7];
    const float* bv = (const float*)d_in[8];
    const float* Wo = (const float*)d_in[9];
    const float* bo = (const float*)d_in[10];
    float* out = (float*)d_out;

    const size_t nH = (size_t)BATCH * NHEAD * SEQ * HDIM;  // 4,194,304
    float* Qh = (float*)d_ws;          // 16.78 MB
    float* Kh = Qh + nH;               // 16.78 MB
    float* Vh = Kh + nH;               // 16.78 MB
    float* AO = Vh + nH;               // 16.78 MB  (total ~67 MB)

    dim3 gg(64, 16), gb(256);
    hipLaunchKernelGGL((proj_gemm<0>), gg, gb, 0, stream, q, Wq, bq, Qh);
    hipLaunchKernelGGL((proj_gemm<0>), gg, gb, 0, stream, k, Wk, bk, Kh);
    hipLaunchKernelGGL((proj_gemm<0>), gg, gb, 0, stream, v, Wv, bv, Vh);
    hipLaunchKernelGGL(attn_topk, dim3(BATCH*NHEAD, SEQ/64), dim3(256), 0, stream,
                       Qh, Kh, Vh, AO);
    hipLaunchKernelGGL((proj_gemm<1>), gg, gb, 0, stream, AO, Wo, bo, out);
}

// Round 16
// 1527.622 us; speedup vs baseline: 1.0740x; 1.0740x over previous
//
#include <hip/hip_runtime.h>
#include <cmath>

#define BATCH  2
#define SEQ    2048
#define DMODEL 1024
#define NHEAD  16
#define HDIM   64
#define KTOP   8
#define KKEEP  10   // global top-8 + slack for bitwise ties at the threshold
#define LKEEP  12   // lane-local FMA-prefilter candidates (margin vs delta)

// KC=512 CONFIRMED bit-exact vs harness numpy reference (rounds 6/8-15 pass).
#define KC_PANEL 512

// ---------------------------------------------------------------------------
// Projection GEMM replicating OpenBLAS sgemm fp32 rounding (KC=512 panels).
// MODE 0: out in head layout [b][h][s][d]; MODE 1: flat [row][col].
// ---------------------------------------------------------------------------
template<int MODE>
__global__ __launch_bounds__(256)
void proj_gemm(const float* __restrict__ A, const float* __restrict__ W,
               const float* __restrict__ bias, float* __restrict__ outp)
{
    __shared__ float As[32][68];   // [k][m]
    __shared__ float Bs[32][68];   // [k][n]
    const int tid  = threadIdx.x;
    const int tx   = tid & 15, ty = tid >> 4;
    const int row0 = blockIdx.x * 64;
    const int col0 = blockIdx.y * 64;
    const int lm   = tid >> 2;          // 0..63
    const int lk   = (tid & 3) * 8;     // 0,8,16,24

    float acc[4][4] = {};   // open panel chain
    float sum[4][4] = {};   // closed panels

    for (int kb = 0; kb < DMODEL; kb += 32) {
        if (kb && (kb % KC_PANEL == 0)) {
            #pragma unroll
            for (int i = 0; i < 4; ++i)
                #pragma unroll
                for (int j = 0; j < 4; ++j) { sum[i][j] += acc[i][j]; acc[i][j] = 0.f; }
        }
        __syncthreads();
        const float* srcA = A + (size_t)(row0 + lm) * DMODEL + kb + lk;
        float4 a0 = *(const float4*)srcA;
        float4 a1 = *(const float4*)(srcA + 4);
        const float* srcB = W + (size_t)(col0 + lm) * DMODEL + kb + lk;
        float4 b0 = *(const float4*)srcB;
        float4 b1 = *(const float4*)(srcB + 4);
        As[lk+0][lm]=a0.x; As[lk+1][lm]=a0.y; As[lk+2][lm]=a0.z; As[lk+3][lm]=a0.w;
        As[lk+4][lm]=a1.x; As[lk+5][lm]=a1.y; As[lk+6][lm]=a1.z; As[lk+7][lm]=a1.w;
        Bs[lk+0][lm]=b0.x; Bs[lk+1][lm]=b0.y; Bs[lk+2][lm]=b0.z; Bs[lk+3][lm]=b0.w;
        Bs[lk+4][lm]=b1.x; Bs[lk+5][lm]=b1.y; Bs[lk+6][lm]=b1.z; Bs[lk+7][lm]=b1.w;
        __syncthreads();
        #pragma unroll
        for (int kk = 0; kk < 32; ++kk) {   // ascending k, fused-FMA chain
            float4 af = *(const float4*)&As[kk][ty*4];
            float4 bf = *(const float4*)&Bs[kk][tx*4];
            float a_[4] = {af.x, af.y, af.z, af.w};
            float b_[4] = {bf.x, bf.y, bf.z, bf.w};
            #pragma unroll
            for (int i = 0; i < 4; ++i)
                #pragma unroll
                for (int j = 0; j < 4; ++j)
                    acc[i][j] = fmaf(a_[i], b_[j], acc[i][j]);
        }
    }

    #pragma unroll
    for (int i = 0; i < 4; ++i) {
        const int row = row0 + ty*4 + i;
        const int bb  = row >> 11;
        const int ss  = row & (SEQ - 1);
        #pragma unroll
        for (int j = 0; j < 4; ++j) {
            const int col = col0 + tx*4 + j;
            float r = sum[i][j] + acc[i][j];   // close final panel
            r = r + bias[col];                 // bias == 0.0f: exact
            if constexpr (MODE == 1) {
                outp[(size_t)row * DMODEL + col] = r;
            } else {
                const int h = col >> 6, d = col & 63;
                outp[(((size_t)(bb*NHEAD + h))*SEQ + ss)*HDIM + d] = r;
            }
        }
    }
}

// ---------------------------------------------------------------------------
// Attention, lane = query row, waves split keys 4-way, 2-deep key prefetch,
// FMA prefilter (R15) + SPILL-FREE exact rescore (new):
//   R15's rescore materialized kb[16] float4 per candidate inside a fully
//   unrolled 12-iter loop; the scheduler overlapped the 12 gather sequences
//   -> ~768 reg demand -> VGPR=256 + 339 MB scratch. Fix: stream each
//   candidate's K row 4 float4s at a time INSIDE the cascade (no kb/ev
//   arrays; rescore fused with the canonical sorted insert, static indexing)
//   and fence candidate iterations with sched_barrier(0) so gathers cannot
//   be hoisted across candidates. Peak extra pressure ~16 regs.
// Selection semantics unchanged vs R14/R15 (passed): exact npyv values,
// canonical (v desc, ix asc) sort, exact 4-way merge, softmax, sparse PV.
// ---------------------------------------------------------------------------
__global__ __launch_bounds__(256, 1)
void attn_topk(const float* __restrict__ Qh, const float* __restrict__ Kh,
               const float* __restrict__ Vh, float* __restrict__ AO)
{
    __shared__ float Ls[4][64][LKEEP + 1];   // +1 pad: 13*4B lane stride
    __shared__ int   Li[4][64][LKEEP + 1];
    const int tid  = threadIdx.x;
    const int lane = tid & 63;
    const int w    = tid >> 6;          // 0..3 (key quarter / dim quarter)
    const int bh   = blockIdx.x;        // 0..31  (XCD = bh % 8)
    const int rg   = blockIdx.y;        // 0..31
    const int srow = rg * 64 + lane;    // this lane's query row
    const size_t hbase = (size_t)bh * SEQ * HDIM;
    const float* Q = Qh + hbase;
    const float* K = Kh + hbase;
    const float* V = Vh + hbase;

    // ---- this lane's q row -> VGPRs ----
    float q[64];
    {
        const float* qsrc = Q + (size_t)srow * HDIM;
        #pragma unroll
        for (int d4 = 0; d4 < 16; ++d4) {
            float4 t4 = *(const float4*)(qsrc + d4*4);
            q[d4*4+0]=t4.x; q[d4*4+1]=t4.y; q[d4*4+2]=t4.z; q[d4*4+3]=t4.w;
        }
    }

    // ---- FMA-prefilter lane-local top-LKEEP over this wave's 512 keys ----
    float fv[LKEEP]; int fi[LKEEP];
    #pragma unroll
    for (int s = 0; s < LKEEP; ++s) { fv[s] = -INFINITY; fi[s] = 0; }

    const int k0 = w * (SEQ/4);

#define LOADKEY(buf, kidx)                                                  \
    do {                                                                    \
        const float* kb_ = K + (size_t)(kidx) * HDIM;                       \
        _Pragma("unroll")                                                   \
        for (int f_ = 0; f_ < 16; ++f_)                                     \
            buf[f_] = *(const float4*)(kb_ + 4*f_);                         \
    } while (0)

#define DOTINS_FMA(buf, kidx)                                               \
    do {                                                                    \
        float A0=0.f, A1=0.f, A2=0.f, A3=0.f;                               \
        _Pragma("unroll")                                                   \
        for (int t_ = 0; t_ < 4; ++t_) {                                    \
            _Pragma("unroll")                                               \
            for (int f_ = 0; f_ < 4; ++f_) {                                \
                const float4 k4_ = buf[t_*4+f_];                            \
                const int u_ = t_*16 + f_*4;                                \
                A0 = fmaf(q[u_+0], k4_.x, A0);                              \
                A1 = fmaf(q[u_+1], k4_.y, A1);                              \
                A2 = fmaf(q[u_+2], k4_.z, A2);                              \
                A3 = fmaf(q[u_+3], k4_.w, A3);                              \
            }                                                               \
        }                                                                   \
        const float cand_ = ((A0 + A1) + (A2 + A3)) * 0.125f;               \
        if (cand_ > fv[LKEEP-1]) {                                          \
            float v_ = cand_; int ix_ = (kidx);                             \
            _Pragma("unroll")                                               \
            for (int s_ = 0; s_ < LKEEP; ++s_) {                            \
                const bool gt_ = v_ > fv[s_];                               \
                const float o1_ = fv[s_]; const int o2_ = fi[s_];           \
                fv[s_] = gt_ ? v_  : o1_;  fi[s_] = gt_ ? ix_ : o2_;        \
                v_     = gt_ ? o1_ : v_;   ix_    = gt_ ? o2_ : ix_;        \
            }                                                               \
        }                                                                   \
    } while (0)

    {
        float4 bufA[16], bufB[16];
        LOADKEY(bufA, k0);                       // prologue: key 0
        for (int c = 0; c < SEQ/4; c += 2) {
            const int c1 = k0 + ((c+1 < SEQ/4) ? c+1 : SEQ/4-1);
            const int c2 = k0 + ((c+2 < SEQ/4) ? c+2 : SEQ/4-1);
            LOADKEY(bufB, c1);                   // issue c+1 loads ...
            DOTINS_FMA(bufA, k0 + c);            // ... under c's compute
            LOADKEY(bufA, c2);                   // issue c+2 loads ...
            DOTINS_FMA(bufB, c1);                // ... under c+1's compute
        }
    }
#undef LOADKEY
#undef DOTINS_FMA

    // ---- EXACT rescore (numpy npyv cascade) fused with canonical insert.
    //      Streams 4 float4 per t-block (no kb[16]/ev[] arrays); candidate
    //      iterations fenced with sched_barrier(0) -> no cross-candidate
    //      gather hoisting (R15's 339 MB spill). All tv/ti indexing static. ----
    float tv[LKEEP]; int ti[LKEEP];
    #pragma unroll
    for (int s = 0; s < LKEEP; ++s) { tv[s] = -INFINITY; ti[s] = 0x7fffffff; }

    #pragma unroll
    for (int s = 0; s < LKEEP; ++s) {
        const float* kr = K + (size_t)fi[s] * HDIM;
        float raw;
        {
            #pragma clang fp contract(off)
            float A0=0.f,A1=0.f,A2=0.f,A3=0.f;
            #pragma unroll
            for (int t = 0; t < 4; ++t) {
                const float4 kb0 = *(const float4*)(kr + t*16 + 0);
                const float4 kb1 = *(const float4*)(kr + t*16 + 4);
                const float4 kb2 = *(const float4*)(kr + t*16 + 8);
                const float4 kb3 = *(const float4*)(kr + t*16 + 12);
                const int u = t*16;
                A0 = q[u+0]*kb0.x + (q[u+4]*kb1.x + (q[u+8]*kb2.x  + (q[u+12]*kb3.x + A0)));
                A1 = q[u+1]*kb0.y + (q[u+5]*kb1.y + (q[u+9]*kb2.y  + (q[u+13]*kb3.y + A1)));
                A2 = q[u+2]*kb0.z + (q[u+6]*kb1.z + (q[u+10]*kb2.z + (q[u+14]*kb3.z + A2)));
                A3 = q[u+3]*kb0.w + (q[u+7]*kb1.w + (q[u+11]*kb2.w + (q[u+15]*kb3.w + A3)));
            }
            raw = (A0 + A1) + (A2 + A3);
        }
        float v = raw * 0.125f;          // exact npyv value, /sqrt(64) exact
        int  ix = fi[s];
        #pragma unroll
        for (int t = 0; t < LKEEP; ++t) {  // canonical insert (v desc, ix asc)
            const bool gt = (v > tv[t]) || (v == tv[t] && ix < ti[t]);
            const float otv = tv[t]; const int oti = ti[t];
            tv[t] = gt ? v  : otv;  ti[t] = gt ? ix  : oti;
            v     = gt ? otv : v;   ix    = gt ? oti : ix;
        }
        __builtin_amdgcn_sched_barrier(0);   // fence: no cross-candidate hoist
    }

    // ---- publish partial lists, one barrier ----
    #pragma unroll
    for (int s = 0; s < LKEEP; ++s) {
        Ls[w][lane][s] = tv[s];
        Li[w][lane][s] = ti[s];
    }
    __syncthreads();

    // ---- exact 4-way merge on EXACT values (pointer-walk, 10 steps) ----
    float gv[KKEEP]; int gi[KKEEP];
    {
        int   hp0 = 0, hp1 = 0, hp2 = 0, hp3 = 0;
        float hv0 = Ls[0][lane][0], hv1 = Ls[1][lane][0],
              hv2 = Ls[2][lane][0], hv3 = Ls[3][lane][0];
        int   hi0 = Li[0][lane][0], hi1 = Li[1][lane][0],
              hi2 = Li[2][lane][0], hi3 = Li[3][lane][0];
        #pragma unroll
        for (int s = 0; s < KKEEP; ++s) {
            float bv = hv0; int bi = hi0; int bj = 0;
            if (hv1 > bv || (hv1 == bv && hi1 < bi)) { bv = hv1; bi = hi1; bj = 1; }
            if (hv2 > bv || (hv2 == bv && hi2 < bi)) { bv = hv2; bi = hi2; bj = 2; }
            if (hv3 > bv || (hv3 == bv && hi3 < bi)) { bv = hv3; bi = hi3; bj = 3; }
            gv[s] = bv; gi[s] = bi;
            {
                const bool a = (bj == 0); const int np = hp0 + (a ? 1 : 0);
                const int  rp = np < LKEEP ? np : LKEEP-1;
                const float nv = Ls[0][lane][rp]; const int ni = Li[0][lane][rp];
                if (a) { hp0 = np; hv0 = (np < LKEEP) ? nv : -INFINITY; hi0 = ni; }
            }
            {
                const bool a = (bj == 1); const int np = hp1 + (a ? 1 : 0);
                const int  rp = np < LKEEP ? np : LKEEP-1;
                const float nv = Ls[1][lane][rp]; const int ni = Li[1][lane][rp];
                if (a) { hp1 = np; hv1 = (np < LKEEP) ? nv : -INFINITY; hi1 = ni; }
            }
            {
                const bool a = (bj == 2); const int np = hp2 + (a ? 1 : 0);
                const int  rp = np < LKEEP ? np : LKEEP-1;
                const float nv = Ls[2][lane][rp]; const int ni = Li[2][lane][rp];
                if (a) { hp2 = np; hv2 = (np < LKEEP) ? nv : -INFINITY; hi2 = ni; }
            }
            {
                const bool a = (bj == 3); const int np = hp3 + (a ? 1 : 0);
                const int  rp = np < LKEEP ? np : LKEEP-1;
                const float nv = Ls[3][lane][rp]; const int ni = Li[3][lane][rp];
                if (a) { hp3 = np; hv3 = (np < LKEEP) ? nv : -INFINITY; hi3 = ni; }
            }
        }
    }

    // ---- per-lane softmax over kept set (identical order to R6-R15) ----
    const float thr = gv[KTOP-1];
    const float m   = gv[0];
    float wv[KKEEP]; float wsum = 0.f;
    #pragma unroll
    for (int s = 0; s < KKEEP; ++s) {
        wv[s] = (gv[s] >= thr) ? expf(gv[s] - m) : 0.f;   // slots 8,9 iff tied
        wsum += wv[s];
    }

    // ---- sparse PV, this wave does dims [w*16, w*16+16) ----
    float o[16];
    #pragma unroll
    for (int d = 0; d < 16; ++d) o[d] = 0.f;
    #pragma unroll
    for (int s = 0; s < KKEEP; ++s) {
        const float wgt = wv[s] / wsum;                  // 0 for non-kept: exact
        const float* vrow = V + (size_t)gi[s] * HDIM + w * 16;
        #pragma unroll
        for (int d4 = 0; d4 < 4; ++d4) {
            float4 vv = *(const float4*)(vrow + d4*4);
            o[d4*4+0] = fmaf(wgt, vv.x, o[d4*4+0]);
            o[d4*4+1] = fmaf(wgt, vv.y, o[d4*4+1]);
            o[d4*4+2] = fmaf(wgt, vv.z, o[d4*4+2]);
            o[d4*4+3] = fmaf(wgt, vv.w, o[d4*4+3]);
        }
    }

    // AO flat layout [b][s][h*64+d]
    float* dst = AO + ((size_t)(bh >> 4) * SEQ + srow) * DMODEL
               + (bh & 15) * HDIM + w * 16;
    #pragma unroll
    for (int d4 = 0; d4 < 4; ++d4) {
        float4 ov; ov.x = o[d4*4+0]; ov.y = o[d4*4+1];
                   ov.z = o[d4*4+2]; ov.w = o[d4*4+3];
        *(float4*)(dst + d4*4) = ov;
    }
}

// ---------------------------------------------------------------------------
extern "C" void kernel_launch(void* const* d_in, const int* in_sizes, int n_in,
                              void* d_out, int out_size, void* d_ws, size_t ws_size,
                              hipStream_t stream)
{
    const float* q  = (const float*)d_in[0];
    const float* k  = (const float*)d_in[1];
    const float* v  = (const float*)d_in[2];
    const float* Wq = (const float*)d_in[3];
    const float* bq = (const float*)d_in[4];
    const float* Wk = (const float*)d_in[5];
    const float* bk = (const float*)d_in[6];
    const float* Wv = (const float*)d_in[7];
    const float* bv = (const float*)d_in[8];
    const float* Wo = (const float*)d_in[9];
    const float* bo = (const float*)d_in[10];
    float* out = (float*)d_out;

    const size_t nH = (size_t)BATCH * NHEAD * SEQ * HDIM;  // 4,194,304
    float* Qh = (float*)d_ws;          // 16.78 MB
    float* Kh = Qh + nH;               // 16.78 MB
    float* Vh = Kh + nH;               // 16.78 MB
    float* AO = Vh + nH;               // 16.78 MB  (total ~67 MB)

    dim3 gg(64, 16), gb(256);
    hipLaunchKernelGGL((proj_gemm<0>), gg, gb, 0, stream, q, Wq, bq, Qh);
    hipLaunchKernelGGL((proj_gemm<0>), gg, gb, 0, stream, k, Wk, bk, Kh);
    hipLaunchKernelGGL((proj_gemm<0>), gg, gb, 0, stream, v, Wv, bv, Vh);
    hipLaunchKernelGGL(attn_topk, dim3(BATCH*NHEAD, SEQ/64), dim3(256), 0, stream,
                       Qh, Kh, Vh, AO);
    hipLaunchKernelGGL((proj_gemm<1>), gg, gb, 0, stream, AO, Wo, bo, out);
}

// Round 17
// 1512.098 us; speedup vs baseline: 1.0850x; 1.0103x over previous
//
#include <hip/hip_runtime.h>
#include <cmath>

#define BATCH  2
#define SEQ    2048
#define DMODEL 1024
#define NHEAD  16
#define HDIM   64
#define KTOP   8
#define KKEEP  10   // global top-8 + slack for bitwise ties at the threshold
#define LKEEP  12   // lane-local FMA-prefilter candidates (margin vs delta)

// KC=512 CONFIRMED bit-exact vs harness numpy reference (rounds 6/8-16 pass).
#define KC_PANEL 512

// ---------------------------------------------------------------------------
// Projection GEMM replicating OpenBLAS sgemm fp32 rounding (KC=512 panels).
// MODE 0: out in head layout [b][h][s][d]; MODE 1: flat [row][col].
// ---------------------------------------------------------------------------
template<int MODE>
__global__ __launch_bounds__(256)
void proj_gemm(const float* __restrict__ A, const float* __restrict__ W,
               const float* __restrict__ bias, float* __restrict__ outp)
{
    __shared__ float As[32][68];   // [k][m]
    __shared__ float Bs[32][68];   // [k][n]
    const int tid  = threadIdx.x;
    const int tx   = tid & 15, ty = tid >> 4;
    const int row0 = blockIdx.x * 64;
    const int col0 = blockIdx.y * 64;
    const int lm   = tid >> 2;          // 0..63
    const int lk   = (tid & 3) * 8;     // 0,8,16,24

    float acc[4][4] = {};   // open panel chain
    float sum[4][4] = {};   // closed panels

    for (int kb = 0; kb < DMODEL; kb += 32) {
        if (kb && (kb % KC_PANEL == 0)) {
            #pragma unroll
            for (int i = 0; i < 4; ++i)
                #pragma unroll
                for (int j = 0; j < 4; ++j) { sum[i][j] += acc[i][j]; acc[i][j] = 0.f; }
        }
        __syncthreads();
        const float* srcA = A + (size_t)(row0 + lm) * DMODEL + kb + lk;
        float4 a0 = *(const float4*)srcA;
        float4 a1 = *(const float4*)(srcA + 4);
        const float* srcB = W + (size_t)(col0 + lm) * DMODEL + kb + lk;
        float4 b0 = *(const float4*)srcB;
        float4 b1 = *(const float4*)(srcB + 4);
        As[lk+0][lm]=a0.x; As[lk+1][lm]=a0.y; As[lk+2][lm]=a0.z; As[lk+3][lm]=a0.w;
        As[lk+4][lm]=a1.x; As[lk+5][lm]=a1.y; As[lk+6][lm]=a1.z; As[lk+7][lm]=a1.w;
        Bs[lk+0][lm]=b0.x; Bs[lk+1][lm]=b0.y; Bs[lk+2][lm]=b0.z; Bs[lk+3][lm]=b0.w;
        Bs[lk+4][lm]=b1.x; Bs[lk+5][lm]=b1.y; Bs[lk+6][lm]=b1.z; Bs[lk+7][lm]=b1.w;
        __syncthreads();
        #pragma unroll
        for (int kk = 0; kk < 32; ++kk) {   // ascending k, fused-FMA chain
            float4 af = *(const float4*)&As[kk][ty*4];
            float4 bf = *(const float4*)&Bs[kk][tx*4];
            float a_[4] = {af.x, af.y, af.z, af.w};
            float b_[4] = {bf.x, bf.y, bf.z, bf.w};
            #pragma unroll
            for (int i = 0; i < 4; ++i)
                #pragma unroll
                for (int j = 0; j < 4; ++j)
                    acc[i][j] = fmaf(a_[i], b_[j], acc[i][j]);
        }
    }

    #pragma unroll
    for (int i = 0; i < 4; ++i) {
        const int row = row0 + ty*4 + i;
        const int bb  = row >> 11;
        const int ss  = row & (SEQ - 1);
        #pragma unroll
        for (int j = 0; j < 4; ++j) {
            const int col = col0 + tx*4 + j;
            float r = sum[i][j] + acc[i][j];   // close final panel
            r = r + bias[col];                 // bias == 0.0f: exact
            if constexpr (MODE == 1) {
                outp[(size_t)row * DMODEL + col] = r;
            } else {
                const int h = col >> 6, d = col & 63;
                outp[(((size_t)(bb*NHEAD + h))*SEQ + ss)*HDIM + d] = r;
            }
        }
    }
}

// ---------------------------------------------------------------------------
// Attention, lane = query row, waves split keys 4-way.
// R17 change: DROP the 128-VGPR bufA/bufB register prefetch; stream each
// key's 4xfloat4 directly into the FMA cascade, and get latency hiding from
// a SECOND RESIDENT WAVE instead.
//   Empirical occupancy rule from R9-R16 counters: waves/SIMD =
//   floor(256/VGPR). R14/15/16 at VGPR 140-256 ran 1 wave/SIMD ->
//   latency-bound plateau ~1100us (VALUBusy 51-68%). Live set without the
//   buffers ~= q(64)+fv/fi(24)+kv(16)+misc(15) ~= 120 <= 128, so
//   __launch_bounds__(256,2) caps the allocator at 128 WITHOUT spilling
//   (R13's (256,2) spill was live-set 230 > cap; here it fits).
// Scan = FMA prefilter (lane-local top-LKEEP); rescore = exact npyv cascade
// fused with canonical insert, sched_barrier-fenced (R16, spill-free);
// exact 4-way merge + softmax + sparse PV unchanged (R12-R16 verified).
// ---------------------------------------------------------------------------
__global__ __launch_bounds__(256, 2)
void attn_topk(const float* __restrict__ Qh, const float* __restrict__ Kh,
               const float* __restrict__ Vh, float* __restrict__ AO)
{
    __shared__ float Ls[4][64][LKEEP + 1];   // +1 pad: 13*4B lane stride
    __shared__ int   Li[4][64][LKEEP + 1];
    const int tid  = threadIdx.x;
    const int lane = tid & 63;
    const int w    = tid >> 6;          // 0..3 (key quarter / dim quarter)
    const int bh   = blockIdx.x;        // 0..31  (XCD = bh % 8)
    const int rg   = blockIdx.y;        // 0..31
    const int srow = rg * 64 + lane;    // this lane's query row
    const size_t hbase = (size_t)bh * SEQ * HDIM;
    const float* Q = Qh + hbase;
    const float* K = Kh + hbase;
    const float* V = Vh + hbase;

    // ---- this lane's q row -> VGPRs ----
    float q[64];
    {
        const float* qsrc = Q + (size_t)srow * HDIM;
        #pragma unroll
        for (int d4 = 0; d4 < 16; ++d4) {
            float4 t4 = *(const float4*)(qsrc + d4*4);
            q[d4*4+0]=t4.x; q[d4*4+1]=t4.y; q[d4*4+2]=t4.z; q[d4*4+3]=t4.w;
        }
    }

    // ---- FMA-prefilter lane-local top-LKEEP over this wave's 512 keys ----
    float fv[LKEEP]; int fi[LKEEP];
    #pragma unroll
    for (int s = 0; s < LKEEP; ++s) { fv[s] = -INFINITY; fi[s] = 0; }

    const int k0 = w * (SEQ/4);

    for (int c = 0; c < SEQ/4; ++c) {
        const float* kr = K + (size_t)(k0 + c) * HDIM;   // wave-uniform addr
        float A0=0.f, A1=0.f, A2=0.f, A3=0.f;
        #pragma unroll
        for (int t = 0; t < 4; ++t) {       // stream 4 float4 per 16-dim block
            const float4 k0v = *(const float4*)(kr + t*16 + 0);
            const float4 k1v = *(const float4*)(kr + t*16 + 4);
            const float4 k2v = *(const float4*)(kr + t*16 + 8);
            const float4 k3v = *(const float4*)(kr + t*16 + 12);
            const int u = t*16;
            A0 = fmaf(q[u+ 0], k0v.x, A0);  A1 = fmaf(q[u+ 1], k0v.y, A1);
            A2 = fmaf(q[u+ 2], k0v.z, A2);  A3 = fmaf(q[u+ 3], k0v.w, A3);
            A0 = fmaf(q[u+ 4], k1v.x, A0);  A1 = fmaf(q[u+ 5], k1v.y, A1);
            A2 = fmaf(q[u+ 6], k1v.z, A2);  A3 = fmaf(q[u+ 7], k1v.w, A3);
            A0 = fmaf(q[u+ 8], k2v.x, A0);  A1 = fmaf(q[u+ 9], k2v.y, A1);
            A2 = fmaf(q[u+10], k2v.z, A2);  A3 = fmaf(q[u+11], k2v.w, A3);
            A0 = fmaf(q[u+12], k3v.x, A0);  A1 = fmaf(q[u+13], k3v.y, A1);
            A2 = fmaf(q[u+14], k3v.z, A2);  A3 = fmaf(q[u+15], k3v.w, A3);
        }
        const float cand = ((A0 + A1) + (A2 + A3)) * 0.125f;
        if (cand > fv[LKEEP-1]) {           // lane-local sorted insert
            float v = cand; int ix = k0 + c;
            #pragma unroll
            for (int s = 0; s < LKEEP; ++s) {
                const bool gt = v > fv[s];
                const float o1 = fv[s]; const int o2 = fi[s];
                fv[s] = gt ? v  : o1;  fi[s] = gt ? ix : o2;
                v     = gt ? o1 : v;   ix    = gt ? o2 : ix;
            }
        }
    }

    // ---- EXACT rescore (numpy npyv cascade) fused with canonical insert.
    //      Streams 4 float4 per t-block; candidate iterations fenced with
    //      sched_barrier(0) -> no cross-candidate gather hoisting (R15's
    //      spill). All tv/ti indexing static. ----
    float tv[LKEEP]; int ti[LKEEP];
    #pragma unroll
    for (int s = 0; s < LKEEP; ++s) { tv[s] = -INFINITY; ti[s] = 0x7fffffff; }

    #pragma unroll
    for (int s = 0; s < LKEEP; ++s) {
        const float* kr = K + (size_t)fi[s] * HDIM;
        float raw;
        {
            #pragma clang fp contract(off)
            float A0=0.f,A1=0.f,A2=0.f,A3=0.f;
            #pragma unroll
            for (int t = 0; t < 4; ++t) {
                const float4 kb0 = *(const float4*)(kr + t*16 + 0);
                const float4 kb1 = *(const float4*)(kr + t*16 + 4);
                const float4 kb2 = *(const float4*)(kr + t*16 + 8);
                const float4 kb3 = *(const float4*)(kr + t*16 + 12);
                const int u = t*16;
                A0 = q[u+0]*kb0.x + (q[u+4]*kb1.x + (q[u+8]*kb2.x  + (q[u+12]*kb3.x + A0)));
                A1 = q[u+1]*kb0.y + (q[u+5]*kb1.y + (q[u+9]*kb2.y  + (q[u+13]*kb3.y + A1)));
                A2 = q[u+2]*kb0.z + (q[u+6]*kb1.z + (q[u+10]*kb2.z + (q[u+14]*kb3.z + A2)));
                A3 = q[u+3]*kb0.w + (q[u+7]*kb1.w + (q[u+11]*kb2.w + (q[u+15]*kb3.w + A3)));
            }
            raw = (A0 + A1) + (A2 + A3);
        }
        float v = raw * 0.125f;          // exact npyv value, /sqrt(64) exact
        int  ix = fi[s];
        #pragma unroll
        for (int t = 0; t < LKEEP; ++t) {  // canonical insert (v desc, ix asc)
            const bool gt = (v > tv[t]) || (v == tv[t] && ix < ti[t]);
            const float otv = tv[t]; const int oti = ti[t];
            tv[t] = gt ? v  : otv;  ti[t] = gt ? ix  : oti;
            v     = gt ? otv : v;   ix    = gt ? oti : ix;
        }
        __builtin_amdgcn_sched_barrier(0);   // fence: no cross-candidate hoist
    }

    // ---- publish partial lists, one barrier ----
    #pragma unroll
    for (int s = 0; s < LKEEP; ++s) {
        Ls[w][lane][s] = tv[s];
        Li[w][lane][s] = ti[s];
    }
    __syncthreads();

    // ---- exact 4-way merge on EXACT values (pointer-walk, 10 steps) ----
    float gv[KKEEP]; int gi[KKEEP];
    {
        int   hp0 = 0, hp1 = 0, hp2 = 0, hp3 = 0;
        float hv0 = Ls[0][lane][0], hv1 = Ls[1][lane][0],
              hv2 = Ls[2][lane][0], hv3 = Ls[3][lane][0];
        int   hi0 = Li[0][lane][0], hi1 = Li[1][lane][0],
              hi2 = Li[2][lane][0], hi3 = Li[3][lane][0];
        #pragma unroll
        for (int s = 0; s < KKEEP; ++s) {
            float bv = hv0; int bi = hi0; int bj = 0;
            if (hv1 > bv || (hv1 == bv && hi1 < bi)) { bv = hv1; bi = hi1; bj = 1; }
            if (hv2 > bv || (hv2 == bv && hi2 < bi)) { bv = hv2; bi = hi2; bj = 2; }
            if (hv3 > bv || (hv3 == bv && hi3 < bi)) { bv = hv3; bi = hi3; bj = 3; }
            gv[s] = bv; gi[s] = bi;
            {
                const bool a = (bj == 0); const int np = hp0 + (a ? 1 : 0);
                const int  rp = np < LKEEP ? np : LKEEP-1;
                const float nv = Ls[0][lane][rp]; const int ni = Li[0][lane][rp];
                if (a) { hp0 = np; hv0 = (np < LKEEP) ? nv : -INFINITY; hi0 = ni; }
            }
            {
                const bool a = (bj == 1); const int np = hp1 + (a ? 1 : 0);
                const int  rp = np < LKEEP ? np : LKEEP-1;
                const float nv = Ls[1][lane][rp]; const int ni = Li[1][lane][rp];
                if (a) { hp1 = np; hv1 = (np < LKEEP) ? nv : -INFINITY; hi1 = ni; }
            }
            {
                const bool a = (bj == 2); const int np = hp2 + (a ? 1 : 0);
                const int  rp = np < LKEEP ? np : LKEEP-1;
                const float nv = Ls[2][lane][rp]; const int ni = Li[2][lane][rp];
                if (a) { hp2 = np; hv2 = (np < LKEEP) ? nv : -INFINITY; hi2 = ni; }
            }
            {
                const bool a = (bj == 3); const int np = hp3 + (a ? 1 : 0);
                const int  rp = np < LKEEP ? np : LKEEP-1;
                const float nv = Ls[3][lane][rp]; const int ni = Li[3][lane][rp];
                if (a) { hp3 = np; hv3 = (np < LKEEP) ? nv : -INFINITY; hi3 = ni; }
            }
        }
    }

    // ---- per-lane softmax over kept set (identical order to R6-R16) ----
    const float thr = gv[KTOP-1];
    const float m   = gv[0];
    float wv[KKEEP]; float wsum = 0.f;
    #pragma unroll
    for (int s = 0; s < KKEEP; ++s) {
        wv[s] = (gv[s] >= thr) ? expf(gv[s] - m) : 0.f;   // slots 8,9 iff tied
        wsum += wv[s];
    }

    // ---- sparse PV, this wave does dims [w*16, w*16+16) ----
    float o[16];
    #pragma unroll
    for (int d = 0; d < 16; ++d) o[d] = 0.f;
    #pragma unroll
    for (int s = 0; s < KKEEP; ++s) {
        const float wgt = wv[s] / wsum;                  // 0 for non-kept: exact
        const float* vrow = V + (size_t)gi[s] * HDIM + w * 16;
        #pragma unroll
        for (int d4 = 0; d4 < 4; ++d4) {
            float4 vv = *(const float4*)(vrow + d4*4);
            o[d4*4+0] = fmaf(wgt, vv.x, o[d4*4+0]);
            o[d4*4+1] = fmaf(wgt, vv.y, o[d4*4+1]);
            o[d4*4+2] = fmaf(wgt, vv.z, o[d4*4+2]);
            o[d4*4+3] = fmaf(wgt, vv.w, o[d4*4+3]);
        }
    }

    // AO flat layout [b][s][h*64+d]
    float* dst = AO + ((size_t)(bh >> 4) * SEQ + srow) * DMODEL
               + (bh & 15) * HDIM + w * 16;
    #pragma unroll
    for (int d4 = 0; d4 < 4; ++d4) {
        float4 ov; ov.x = o[d4*4+0]; ov.y = o[d4*4+1];
                   ov.z = o[d4*4+2]; ov.w = o[d4*4+3];
        *(float4*)(dst + d4*4) = ov;
    }
}

// ---------------------------------------------------------------------------
extern "C" void kernel_launch(void* const* d_in, const int* in_sizes, int n_in,
                              void* d_out, int out_size, void* d_ws, size_t ws_size,
                              hipStream_t stream)
{
    const float* q  = (const float*)d_in[0];
    const float* k  = (const float*)d_in[1];
    const float* v  = (const float*)d_in[2];
    const float* Wq = (const float*)d_in[3];
    const float* bq = (const float*)d_in[4];
    const float* Wk = (const float*)d_in[5];
    const float* bk = (const float*)d_in[6];
    const float* Wv = (const float*)d_in[7];
    const float* bv = (const float*)d_in[8];
    const float* Wo = (const float*)d_in[9];
    const float* bo = (const float*)d_in[10];
    float* out = (float*)d_out;

    const size_t nH = (size_t)BATCH * NHEAD * SEQ * HDIM;  // 4,194,304
    float* Qh = (float*)d_ws;          // 16.78 MB
    float* Kh = Qh + nH;               // 16.78 MB
    float* Vh = Kh + nH;               // 16.78 MB
    float* AO = Vh + nH;               // 16.78 MB  (total ~67 MB)

    dim3 gg(64, 16), gb(256);
    hipLaunchKernelGGL((proj_gemm<0>), gg, gb, 0, stream, q, Wq, bq, Qh);
    hipLaunchKernelGGL((proj_gemm<0>), gg, gb, 0, stream, k, Wk, bk, Kh);
    hipLaunchKernelGGL((proj_gemm<0>), gg, gb, 0, stream, v, Wv, bv, Vh);
    hipLaunchKernelGGL(attn_topk, dim3(BATCH*NHEAD, SEQ/64), dim3(256), 0, stream,
                       Qh, Kh, Vh, AO);
    hipLaunchKernelGGL((proj_gemm<1>), gg, gb, 0, stream, AO, Wo, bo, out);
}